// Round 10
// baseline (376.012 us; speedup 1.0000x reference)
//
#include <hip/hip_runtime.h>
#include <stdint.h>

#define S_LEN 2048
#define EMB   2048
#define NHEAD 32
#define HDIM  64
#define QKVN  3072   // 2048 q + 512 k + 512 v
#define KOFF  2048
#define VOFF  2560

typedef __attribute__((ext_vector_type(8))) short short8;
typedef __attribute__((ext_vector_type(4))) short short4v;
typedef __attribute__((ext_vector_type(4))) float f32x4;

__device__ __forceinline__ unsigned short f2bf(float f) {
  union { float f; unsigned u; } v; v.f = f;
  return (unsigned short)((v.u + 0x7fffu + ((v.u >> 16) & 1u)) >> 16);
}

__device__ __forceinline__ f32x4 mfma16(short8 a, short8 b, f32x4 c) {
  return __builtin_amdgcn_mfma_f32_16x16x32_bf16(a, b, c, 0, 0, 0);
}

__device__ __forceinline__ void gload_lds16(const void* g, void* l) {
  __builtin_amdgcn_global_load_lds(
      (const __attribute__((address_space(1))) void*)g,
      (__attribute__((address_space(3))) void*)l, 16, 0, 0);
}

__device__ __forceinline__ unsigned cvt_pk_bf16(float lo, float hi) {
  unsigned r;
  asm("v_cvt_pk_bf16_f32 %0, %1, %2" : "=v"(r) : "v"(lo), "v"(hi));
  return r;
}

__device__ __forceinline__ float bf16lo_f32(unsigned u) {
  return __builtin_bit_cast(float, u << 16);
}
__device__ __forceinline__ float bf16hi_f32(unsigned u) {
  return __builtin_bit_cast(float, u & 0xffff0000u);
}

// ---------------- fused fp32 -> bf16 convert (all 5 tensors) ----------------
__global__ __launch_bounds__(256) void k_cvt_all(
    const float* __restrict__ x, const float* __restrict__ Wq,
    const float* __restrict__ Wk, const float* __restrict__ Wv,
    const float* __restrict__ Wo, unsigned short* __restrict__ xb,
    unsigned short* __restrict__ wqkv, unsigned short* __restrict__ wob) {
  long i = (long)(blockIdx.x * blockDim.x + threadIdx.x) * 4;
  const float* src; unsigned short* dst; long off;
  if (i < 4194304L)       { src = x;  dst = xb;             off = i; }
  else if (i < 8388608L)  { src = Wq; dst = wqkv;           off = i - 4194304L; }
  else if (i < 9437184L)  { src = Wk; dst = wqkv + 4194304; off = i - 8388608L; }
  else if (i < 10485760L) { src = Wv; dst = wqkv + 5242880; off = i - 9437184L; }
  else                    { src = Wo; dst = wob;            off = i - 10485760L; }
  float4 v = *reinterpret_cast<const float4*>(src + off);
  short4v o;
  o.x = (short)f2bf(v.x); o.y = (short)f2bf(v.y);
  o.z = (short)f2bf(v.z); o.w = (short)f2bf(v.w);
  *reinterpret_cast<short4v*>(dst + off) = o;
}

__global__ void k_bias_cat(const float* __restrict__ bq, const float* __restrict__ bk,
                           const float* __restrict__ bv, float* __restrict__ dst) {
  int i = blockIdx.x * blockDim.x + threadIdx.x;   // grid covers exactly 3072
  if (i < 2048) dst[i] = bq[i];
  else if (i < 2560) dst[i] = bk[i - 2048];
  else dst[i] = bv[i - 2560];
}

// ---------------- GEMM: C[M,N] = A[M,K] @ B[N,K]^T + bias ----------------
template <typename OUT_T>
__global__ __launch_bounds__(256) void k_gemm_bt(
    const unsigned short* __restrict__ A, const unsigned short* __restrict__ B,
    const float* __restrict__ bias, OUT_T* __restrict__ C, int M, int N, int K) {
  __shared__ unsigned short As[128 * 32];
  __shared__ unsigned short Bs[128 * 32];
  const int t = threadIdx.x;
  const int l = t & 63;
  const int w = t >> 6;
  const int m0 = blockIdx.x * 128;
  const int n0 = blockIdx.y * 128;
  const int wm = w >> 1, wn = w & 1;

  f32x4 acc[4][4] = {};

  const unsigned short* ga0 = A + (size_t)(m0 + (t >> 2)) * K + (t & 3) * 8;
  const unsigned short* ga1 = ga0 + (size_t)64 * K;
  const unsigned short* gb0 = B + (size_t)(n0 + (t >> 2)) * K + (t & 3) * 8;
  const unsigned short* gb1 = gb0 + (size_t)64 * K;
  unsigned short* la0 = As + t * 8;
  unsigned short* la1 = As + 2048 + t * 8;
  unsigned short* lb0 = Bs + t * 8;
  unsigned short* lb1 = Bs + 2048 + t * 8;

  const int lr = l & 15;
  const int lk = (l >> 4) * 8;
  const unsigned short* arow = As + (wm * 64 + lr) * 32 + lk;
  const unsigned short* brow = Bs + (wn * 64 + lr) * 32 + lk;

  for (int k0 = 0; k0 < K; k0 += 32) {
    gload_lds16(ga0, la0);
    gload_lds16(ga1, la1);
    gload_lds16(gb0, lb0);
    gload_lds16(gb1, lb1);
    ga0 += 32; ga1 += 32; gb0 += 32; gb1 += 32;
    __syncthreads();
    short8 af[4], bfv[4];
#pragma unroll
    for (int i = 0; i < 4; i++) {
      af[i]  = *reinterpret_cast<const short8*>(arow + i * 16 * 32);
      bfv[i] = *reinterpret_cast<const short8*>(brow + i * 16 * 32);
    }
#pragma unroll
    for (int i = 0; i < 4; i++)
#pragma unroll
      for (int j = 0; j < 4; j++)
        acc[i][j] = mfma16(af[i], bfv[j], acc[i][j]);
    __syncthreads();
  }

  const int lg = l >> 4;
#pragma unroll
  for (int i = 0; i < 4; i++) {
#pragma unroll
    for (int j = 0; j < 4; j++) {
      int col = n0 + wn * 64 + j * 16 + lr;
      float bb = bias[col];
#pragma unroll
      for (int r = 0; r < 4; r++) {
        int row = m0 + wm * 64 + i * 16 + lg * 4 + r;
        float val = acc[i][j][r] + bb;
        if constexpr (sizeof(OUT_T) == 2)
          C[(size_t)row * N + col] = (OUT_T)f2bf(val);
        else
          C[(size_t)row * N + col] = (OUT_T)val;
      }
    }
  }
}

// ---------------- K compaction into swizzled per-(group,chunk) tiles --------
__global__ __launch_bounds__(256) void k_kc(const unsigned short* __restrict__ qkv,
                                            unsigned short* __restrict__ kc) {
  const int gi = blockIdx.x >> 4;       // group
  const int c  = blockIdx.x & 15;       // k-chunk
  const int t = threadIdx.x;
  const int row = t & 127;
  const int part = t >> 7;              // 0/1 (cols 0-31 / 32-63)
  const unsigned short* src =
      qkv + (size_t)(c * 128 + row) * QKVN + KOFF + gi * 64 + part * 32;
  char* dst = (char*)kc + ((size_t)(gi * 16 + c) << 14);
  const int swz = (row & 7) << 4;
#pragma unroll
  for (int j = 0; j < 4; ++j) {
    short8 v = *reinterpret_cast<const short8*>(src + j * 8);
    int b = (row * 128 + part * 64 + j * 16) ^ swz;
    *reinterpret_cast<short8*>(dst + b) = v;
  }
}

// ---------------- V transpose -> swizzled per-(group,chunk) tiles -----------
__global__ __launch_bounds__(256) void k_vT(const unsigned short* __restrict__ qkv,
                                            unsigned short* __restrict__ vt) {
  __shared__ unsigned short tile[64][72];
  const int t = threadIdx.x;
  const int p0 = (blockIdx.x & 31) * 64;
  const int g0 = (blockIdx.x >> 5) * 64;
  {
    const int pl = t >> 3;
    const int gl = (t & 7) * 8;
#pragma unroll
    for (int i = 0; i < 2; i++) {
      int p = pl + i * 32;
      short8 v = *reinterpret_cast<const short8*>(qkv + (size_t)(p0 + p) * QKVN + VOFF + g0 + gl);
#pragma unroll
      for (int j = 0; j < 8; j++) tile[p][gl + j] = (unsigned short)v[j];
    }
  }
  __syncthreads();
  {
    const int gr = t >> 3;
    const int pc = (t & 7) * 8;
    const int cb = pc & ~31;
    const int rbase = pc & 31;
    const int chunk = p0 >> 7;
    const int colin = (p0 & 64) + pc;    // col within 128-chunk
    const int grp = g0 >> 6;
#pragma unroll
    for (int i = 0; i < 2; i++) {
      int g = gr + i * 32;               // row in tile (gd within group)
      short8 o;
#pragma unroll
      for (int j = 0; j < 8; j++) {
        int rp = rbase + j;
        int q8 = rp >> 3, jj = rp & 7;
        int src = cb + ((jj < 4) ? (q8 * 4 + jj) : (16 + q8 * 4 + (jj - 4)));
        o[j] = (short)tile[src][g];
      }
      int b = (g * 256 + colin * 2) ^ ((g & 7) << 4);
      *reinterpret_cast<short8*>(
          (char*)vt + (((size_t)(grp * 16 + chunk)) << 14) + b) = o;
    }
  }
}

// ---------------- fused attention v10 ----------------------------------------
// Changes vs v9 (which removed the gathers): (1) wave = 32 q-rows (2 Q-sets
// share every K/V fragment read -> per-CU ds_read bytes halve); (2) bpermute
// store repack DELETED (plain f32x4 stores; shape proven neutral r5-r7, and
// the 2^23 SQ_LDS_BANK_CONFLICT was the bpermutes); (3) double-buffered tiles
// + counted vmcnt (stage issued BEFORE stores; end-of-chunk wait vmcnt(16)
// retires stage loads, leaves the 16 stores in flight across the barrier).
// Block = 256 thr (4 waves) = one (group, 4 wave-units); g = bid&7 XCD-pin.
__global__ __launch_bounds__(256, 2) void k_attn(
    const unsigned short* __restrict__ qkv, const unsigned short* __restrict__ kc,
    const unsigned short* __restrict__ vt, float* __restrict__ attn_w,
    unsigned short* __restrict__ hout) {
  __shared__ unsigned short Kt[2][8192];   // 2 x 16 KB
  __shared__ unsigned short Vt[2][8192];   // 2 x 16 KB
  const int t = threadIdx.x;
  const int l = t & 63;
  const int w = t >> 6;                    // wave 0..3
  const int g = blockIdx.x & 7;            // group == XCD
  const int bi = blockIdx.x >> 3;          // 0..63
  const int u = bi * 4 + w;                // unit 0..255
  const int h = g * 4 + (u & 3);           // head
  const int r0 = (u >> 2) * 32;            // q-row base (32 rows per wave)
  const int lr = l & 15;
  const int lg = l >> 4;                   // 0..3
  const int lk = lg * 8;
  const int swz = (lr & 7) << 4;

  // Q fragments, 2 sets: rows r0+lr and r0+16+lr
  const unsigned short* qA = qkv + (size_t)(r0 + lr) * QKVN + h * HDIM + lk;
  const unsigned short* qB = qA + (size_t)16 * QKVN;
  const short8 bqA0 = *reinterpret_cast<const short8*>(qA);
  const short8 bqA1 = *reinterpret_cast<const short8*>(qA + 32);
  const short8 bqB0 = *reinterpret_cast<const short8*>(qB);
  const short8 bqB1 = *reinterpret_cast<const short8*>(qB + 32);

  const char* kcg = (const char*)kc + ((size_t)(g * 16) << 14);
  const char* vtg = (const char*)vt + ((size_t)(g * 16) << 14);

#define STAGE_K(c, b)                                                     \
  { const char* s_ = kcg + ((size_t)(c) << 14);                           \
    char* d_ = (char*)Kt[b];                                              \
    _Pragma("unroll")                                                     \
    for (int j_ = 0; j_ < 4; ++j_)                                        \
      gload_lds16(s_ + j_ * 4096 + t * 16, d_ + j_ * 4096 + t * 16); }
#define STAGE_V(c, b)                                                     \
  { const char* s_ = vtg + ((size_t)(c) << 14);                           \
    char* d_ = (char*)Vt[b];                                              \
    _Pragma("unroll")                                                     \
    for (int j_ = 0; j_ < 4; ++j_)                                        \
      gload_lds16(s_ + j_ * 4096 + t * 16, d_ + j_ * 4096 + t * 16); }

  // ================= pass A: online row max + sum (K only, dbuf) ===========
  float mA = -1e30f, smA = 0.f, mB = -1e30f, smB = 0.f;
  STAGE_K(0, 0);
  __syncthreads();
  for (int c = 0; c < 16; ++c) {
    if (c < 15) STAGE_K(c + 1, (c + 1) & 1);    // prefetch overlaps compute
    const char* kb = (const char*)Kt[c & 1];
    f32x4 aA[8], aB[8];
#pragma unroll
    for (int i = 0; i < 8; ++i) {
      int rb = ((i * 16 + lr) << 7) + (lg << 4);
      short8 a0 = *reinterpret_cast<const short8*>(kb + (rb ^ swz));
      short8 a1 = *reinterpret_cast<const short8*>(kb + ((rb + 64) ^ swz));
      f32x4 x = {};
      x = mfma16(a0, bqA0, x);
      x = mfma16(a1, bqA1, x);
      aA[i] = x * 0.125f;
      f32x4 y = {};
      y = mfma16(a0, bqB0, y);
      y = mfma16(a1, bqB1, y);
      aB[i] = y * 0.125f;
    }
    float mcA = -1e30f, mcB = -1e30f;
#pragma unroll
    for (int i = 0; i < 8; ++i) {
      mcA = fmaxf(mcA, fmaxf(fmaxf(aA[i][0], aA[i][1]), fmaxf(aA[i][2], aA[i][3])));
      mcB = fmaxf(mcB, fmaxf(fmaxf(aB[i][0], aB[i][1]), fmaxf(aB[i][2], aB[i][3])));
    }
    mcA = fmaxf(mcA, __shfl_xor(mcA, 16, 64));
    mcA = fmaxf(mcA, __shfl_xor(mcA, 32, 64));
    mcB = fmaxf(mcB, __shfl_xor(mcB, 16, 64));
    mcB = fmaxf(mcB, __shfl_xor(mcB, 32, 64));
    float nmA = fmaxf(mA, mcA);
    float nmB = fmaxf(mB, mcB);
    float psA = 0.f, psB = 0.f;
#pragma unroll
    for (int i = 0; i < 8; ++i) {
#pragma unroll
      for (int r = 0; r < 4; ++r) {
        psA += __expf(aA[i][r] - nmA);
        psB += __expf(aB[i][r] - nmB);
      }
    }
    psA += __shfl_xor(psA, 16, 64);
    psA += __shfl_xor(psA, 32, 64);
    psB += __shfl_xor(psB, 16, 64);
    psB += __shfl_xor(psB, 32, 64);
    smA = smA * __expf(mA - nmA) + psA;
    smB = smB * __expf(mB - nmB) + psB;
    mA = nmA; mB = nmB;
    __syncthreads();                // waits prefetch (vmcnt 0) + all reads done
  }
  const float invA = 1.0f / smA;
  const float invB = 1.0f / smB;

  // ================= pass B: recompute P, store attn, PV (K+V, dbuf) =======
  f32x4 pvA0 = {}, pvA1 = {}, pvA2 = {}, pvA3 = {};
  f32x4 pvB0 = {}, pvB1 = {}, pvB2 = {}, pvB3 = {};
  float* aoutA = attn_w + (size_t)h * S_LEN * S_LEN + (size_t)(r0 + lr) * S_LEN;
  float* aoutB = aoutA + (size_t)16 * S_LEN;

  STAGE_K(0, 0);
  STAGE_V(0, 0);
  __syncthreads();
  for (int c = 0; c < 16; ++c) {
    const char* kb = (const char*)Kt[c & 1];
    const char* vb = (const char*)Vt[c & 1];
    const int kcol = c * 128;
    union A8 { short8 s; unsigned u[4]; } paA[4], paB[4];
    // --- QK^T recompute + normalize + pack (no stores yet) ---
#pragma unroll
    for (int i = 0; i < 8; ++i) {
      int rb = ((i * 16 + lr) << 7) + (lg << 4);
      short8 a0 = *reinterpret_cast<const short8*>(kb + (rb ^ swz));
      short8 a1 = *reinterpret_cast<const short8*>(kb + ((rb + 64) ^ swz));
      f32x4 x = {};
      x = mfma16(a0, bqA0, x);
      x = mfma16(a1, bqA1, x);
      f32x4 y = {};
      y = mfma16(a0, bqB0, y);
      y = mfma16(a1, bqB1, y);
      float pA0 = __expf(x[0] * 0.125f - mA) * invA;
      float pA1 = __expf(x[1] * 0.125f - mA) * invA;
      float pA2 = __expf(x[2] * 0.125f - mA) * invA;
      float pA3 = __expf(x[3] * 0.125f - mA) * invA;
      paA[i >> 1].u[(i & 1) * 2 + 0] = cvt_pk_bf16(pA0, pA1);
      paA[i >> 1].u[(i & 1) * 2 + 1] = cvt_pk_bf16(pA2, pA3);
      float pB0 = __expf(y[0] * 0.125f - mB) * invB;
      float pB1 = __expf(y[1] * 0.125f - mB) * invB;
      float pB2 = __expf(y[2] * 0.125f - mB) * invB;
      float pB3 = __expf(y[3] * 0.125f - mB) * invB;
      paB[i >> 1].u[(i & 1) * 2 + 0] = cvt_pk_bf16(pB0, pB1);
      paB[i >> 1].u[(i & 1) * 2 + 1] = cvt_pk_bf16(pB2, pB3);
    }
    // --- stage next tiles BEFORE stores (vmcnt in-order: loads retire 1st) --
    if (c < 15) { STAGE_K(c + 1, (c + 1) & 1); STAGE_V(c + 1, (c + 1) & 1); }
    // --- attn stores: plain f32x4 (L2 merges lines; no repack) ---
#pragma unroll
    for (int s = 0; s < 4; ++s) {
      f32x4 X, Y;
      X[0] = bf16lo_f32(paA[s].u[0]); X[1] = bf16hi_f32(paA[s].u[0]);
      X[2] = bf16lo_f32(paA[s].u[1]); X[3] = bf16hi_f32(paA[s].u[1]);
      Y[0] = bf16lo_f32(paA[s].u[2]); Y[1] = bf16hi_f32(paA[s].u[2]);
      Y[2] = bf16lo_f32(paA[s].u[3]); Y[3] = bf16hi_f32(paA[s].u[3]);
      *reinterpret_cast<f32x4*>(aoutA + kcol + s * 32 + lg * 4) = X;
      *reinterpret_cast<f32x4*>(aoutA + kcol + s * 32 + 16 + lg * 4) = Y;
      X[0] = bf16lo_f32(paB[s].u[0]); X[1] = bf16hi_f32(paB[s].u[0]);
      X[2] = bf16lo_f32(paB[s].u[1]); X[3] = bf16hi_f32(paB[s].u[1]);
      Y[0] = bf16lo_f32(paB[s].u[2]); Y[1] = bf16hi_f32(paB[s].u[2]);
      Y[2] = bf16lo_f32(paB[s].u[3]); Y[3] = bf16hi_f32(paB[s].u[3]);
      *reinterpret_cast<f32x4*>(aoutB + kcol + s * 32 + lg * 4) = X;
      *reinterpret_cast<f32x4*>(aoutB + kcol + s * 32 + 16 + lg * 4) = Y;
    }
    // --- PV: 16 B-frag reads power 32 MFMA (both q-sets) ---
#pragma unroll
    for (int s = 0; s < 4; ++s) {
      int cbyte = s * 64 + (lg << 4);
      short8 b0 = *reinterpret_cast<const short8*>(vb + ((((lr) << 8) + cbyte) ^ swz));
      short8 b1 = *reinterpret_cast<const short8*>(vb + ((((16 + lr) << 8) + cbyte) ^ swz));
      short8 b2 = *reinterpret_cast<const short8*>(vb + ((((32 + lr) << 8) + cbyte) ^ swz));
      short8 b3 = *reinterpret_cast<const short8*>(vb + ((((48 + lr) << 8) + cbyte) ^ swz));
      pvA0 = mfma16(paA[s].s, b0, pvA0);
      pvA1 = mfma16(paA[s].s, b1, pvA1);
      pvA2 = mfma16(paA[s].s, b2, pvA2);
      pvA3 = mfma16(paA[s].s, b3, pvA3);
      pvB0 = mfma16(paB[s].s, b0, pvB0);
      pvB1 = mfma16(paB[s].s, b1, pvB1);
      pvB2 = mfma16(paB[s].s, b2, pvB2);
      pvB3 = mfma16(paB[s].s, b3, pvB3);
    }
    // --- counted wait: retire stage loads, keep this chunk's stores live ---
    if (c < 15) {
      asm volatile("s_waitcnt vmcnt(16) lgkmcnt(0)\n\ts_barrier" ::: "memory");
      __builtin_amdgcn_sched_barrier(0);
    }
  }

  // ---- hout: lane holds out[q][hd=ht*16+lr]; full k per wave -> no reduce --
  unsigned short* hbA = hout + (size_t)(r0 + lg * 4) * EMB + h * HDIM + lr;
  unsigned short* hbB = hbA + (size_t)16 * EMB;
#pragma unroll
  for (int r = 0; r < 4; ++r) {
    hbA[(size_t)r * EMB +  0] = f2bf(pvA0[r]);
    hbA[(size_t)r * EMB + 16] = f2bf(pvA1[r]);
    hbA[(size_t)r * EMB + 32] = f2bf(pvA2[r]);
    hbA[(size_t)r * EMB + 48] = f2bf(pvA3[r]);
    hbB[(size_t)r * EMB +  0] = f2bf(pvB0[r]);
    hbB[(size_t)r * EMB + 16] = f2bf(pvB1[r]);
    hbB[(size_t)r * EMB + 32] = f2bf(pvB2[r]);
    hbB[(size_t)r * EMB + 48] = f2bf(pvB3[r]);
  }
#undef STAGE_K
#undef STAGE_V
}

extern "C" void kernel_launch(void* const* d_in, const int* in_sizes, int n_in,
                              void* d_out, int out_size, void* d_ws, size_t ws_size,
                              hipStream_t stream) {
  const float* x  = (const float*)d_in[0];
  const float* Wq = (const float*)d_in[1];
  const float* bq = (const float*)d_in[2];
  const float* Wk = (const float*)d_in[3];
  const float* bk = (const float*)d_in[4];
  const float* Wv = (const float*)d_in[5];
  const float* bv = (const float*)d_in[6];
  const float* Wo = (const float*)d_in[7];
  const float* bo = (const float*)d_in[8];
  float* out = (float*)d_out;

  char* ws = (char*)d_ws;
  unsigned short* x_bf  = (unsigned short*)(ws);                 // 8 MiB
  unsigned short* wqkv  = (unsigned short*)(ws + (8ull  << 20)); // 12 MiB
  unsigned short* wo_bf = (unsigned short*)(ws + (20ull << 20)); // 8 MiB
  float*          bqkv  = (float*)         (ws + (28ull << 20)); // 12 KiB
  unsigned short* qkv   = (unsigned short*)(ws + (29ull << 20)); // 12 MiB
  unsigned short* vt_b  = (unsigned short*)(ws + (41ull << 20)); // 2 MiB
  unsigned short* hout  = (unsigned short*)(ws + (43ull << 20)); // 8 MiB
  unsigned short* kc_b  = (unsigned short*)(ws + (51ull << 20)); // 2 MiB

  k_cvt_all<<<14336, 256, 0, stream>>>(x, Wq, Wk, Wv, Wo, x_bf, wqkv, wo_bf);
  k_bias_cat<<<12, 256, 0, stream>>>(bq, bk, bv, bqkv);

  dim3 g1(16, 24);  // M/128 x N/128
  k_gemm_bt<unsigned short><<<g1, 256, 0, stream>>>(x_bf, wqkv, bqkv, qkv, 2048, 3072, 2048);
  k_kc<<<128, 256, 0, stream>>>(qkv, kc_b);
  k_vT<<<256, 256, 0, stream>>>(qkv, vt_b);
  k_attn<<<512, 256, 0, stream>>>(qkv, kc_b, vt_b, out, hout);
  dim3 g2(16, 16);
  k_gemm_bt<float><<<g2, 256, 0, stream>>>(hout, wo_bf, bo, out + (size_t)NHEAD * S_LEN * S_LEN, 2048, 2048, 2048);
}

// Round 11
// 355.239 us; speedup vs baseline: 1.0585x; 1.0585x over previous
//
#include <hip/hip_runtime.h>
#include <stdint.h>

#define S_LEN 2048
#define EMB   2048
#define NHEAD 32
#define HDIM  64
#define QKVN  3072   // 2048 q + 512 k + 512 v
#define KOFF  2048
#define VOFF  2560

typedef __attribute__((ext_vector_type(8))) short short8;
typedef __attribute__((ext_vector_type(4))) short short4v;
typedef __attribute__((ext_vector_type(4))) float f32x4;

__device__ __forceinline__ unsigned short f2bf(float f) {
  union { float f; unsigned u; } v; v.f = f;
  return (unsigned short)((v.u + 0x7fffu + ((v.u >> 16) & 1u)) >> 16);
}

__device__ __forceinline__ f32x4 mfma16(short8 a, short8 b, f32x4 c) {
  return __builtin_amdgcn_mfma_f32_16x16x32_bf16(a, b, c, 0, 0, 0);
}

__device__ __forceinline__ void gload_lds16(const void* g, void* l) {
  __builtin_amdgcn_global_load_lds(
      (const __attribute__((address_space(1))) void*)g,
      (__attribute__((address_space(3))) void*)l, 16, 0, 0);
}

__device__ __forceinline__ unsigned cvt_pk_bf16(float lo, float hi) {
  unsigned r;
  asm("v_cvt_pk_bf16_f32 %0, %1, %2" : "=v"(r) : "v"(lo), "v"(hi));
  return r;
}

__device__ __forceinline__ float bf16lo_f32(unsigned u) {
  return __builtin_bit_cast(float, u << 16);
}
__device__ __forceinline__ float bf16hi_f32(unsigned u) {
  return __builtin_bit_cast(float, u & 0xffff0000u);
}

// ---------------- fused fp32 -> bf16 convert (all 5 tensors) ----------------
__global__ __launch_bounds__(256) void k_cvt_all(
    const float* __restrict__ x, const float* __restrict__ Wq,
    const float* __restrict__ Wk, const float* __restrict__ Wv,
    const float* __restrict__ Wo, unsigned short* __restrict__ xb,
    unsigned short* __restrict__ wqkv, unsigned short* __restrict__ wob) {
  long i = (long)(blockIdx.x * blockDim.x + threadIdx.x) * 4;
  const float* src; unsigned short* dst; long off;
  if (i < 4194304L)       { src = x;  dst = xb;             off = i; }
  else if (i < 8388608L)  { src = Wq; dst = wqkv;           off = i - 4194304L; }
  else if (i < 9437184L)  { src = Wk; dst = wqkv + 4194304; off = i - 8388608L; }
  else if (i < 10485760L) { src = Wv; dst = wqkv + 5242880; off = i - 9437184L; }
  else                    { src = Wo; dst = wob;            off = i - 10485760L; }
  float4 v = *reinterpret_cast<const float4*>(src + off);
  short4v o;
  o.x = (short)f2bf(v.x); o.y = (short)f2bf(v.y);
  o.z = (short)f2bf(v.z); o.w = (short)f2bf(v.w);
  *reinterpret_cast<short4v*>(dst + off) = o;
}

__global__ void k_bias_cat(const float* __restrict__ bq, const float* __restrict__ bk,
                           const float* __restrict__ bv, float* __restrict__ dst) {
  int i = blockIdx.x * blockDim.x + threadIdx.x;   // grid covers exactly 3072
  if (i < 2048) dst[i] = bq[i];
  else if (i < 2560) dst[i] = bk[i - 2048];
  else dst[i] = bv[i - 2560];
}

// ---------------- GEMM: C[M,N] = A[M,K] @ B[N,K]^T + bias ----------------
template <typename OUT_T>
__global__ __launch_bounds__(256) void k_gemm_bt(
    const unsigned short* __restrict__ A, const unsigned short* __restrict__ B,
    const float* __restrict__ bias, OUT_T* __restrict__ C, int M, int N, int K) {
  __shared__ unsigned short As[128 * 32];
  __shared__ unsigned short Bs[128 * 32];
  const int t = threadIdx.x;
  const int l = t & 63;
  const int w = t >> 6;
  const int m0 = blockIdx.x * 128;
  const int n0 = blockIdx.y * 128;
  const int wm = w >> 1, wn = w & 1;

  f32x4 acc[4][4] = {};

  const unsigned short* ga0 = A + (size_t)(m0 + (t >> 2)) * K + (t & 3) * 8;
  const unsigned short* ga1 = ga0 + (size_t)64 * K;
  const unsigned short* gb0 = B + (size_t)(n0 + (t >> 2)) * K + (t & 3) * 8;
  const unsigned short* gb1 = gb0 + (size_t)64 * K;
  unsigned short* la0 = As + t * 8;
  unsigned short* la1 = As + 2048 + t * 8;
  unsigned short* lb0 = Bs + t * 8;
  unsigned short* lb1 = Bs + 2048 + t * 8;

  const int lr = l & 15;
  const int lk = (l >> 4) * 8;
  const unsigned short* arow = As + (wm * 64 + lr) * 32 + lk;
  const unsigned short* brow = Bs + (wn * 64 + lr) * 32 + lk;

  for (int k0 = 0; k0 < K; k0 += 32) {
    gload_lds16(ga0, la0);
    gload_lds16(ga1, la1);
    gload_lds16(gb0, lb0);
    gload_lds16(gb1, lb1);
    ga0 += 32; ga1 += 32; gb0 += 32; gb1 += 32;
    __syncthreads();
    short8 af[4], bfv[4];
#pragma unroll
    for (int i = 0; i < 4; i++) {
      af[i]  = *reinterpret_cast<const short8*>(arow + i * 16 * 32);
      bfv[i] = *reinterpret_cast<const short8*>(brow + i * 16 * 32);
    }
#pragma unroll
    for (int i = 0; i < 4; i++)
#pragma unroll
      for (int j = 0; j < 4; j++)
        acc[i][j] = mfma16(af[i], bfv[j], acc[i][j]);
    __syncthreads();
  }

  const int lg = l >> 4;
#pragma unroll
  for (int i = 0; i < 4; i++) {
#pragma unroll
    for (int j = 0; j < 4; j++) {
      int col = n0 + wn * 64 + j * 16 + lr;
      float bb = bias[col];
#pragma unroll
      for (int r = 0; r < 4; r++) {
        int row = m0 + wm * 64 + i * 16 + lg * 4 + r;
        float val = acc[i][j][r] + bb;
        if constexpr (sizeof(OUT_T) == 2)
          C[(size_t)row * N + col] = (OUT_T)f2bf(val);
        else
          C[(size_t)row * N + col] = (OUT_T)val;
      }
    }
  }
}

// ---------------- K compaction into swizzled per-(group,chunk) tiles --------
__global__ __launch_bounds__(256) void k_kc(const unsigned short* __restrict__ qkv,
                                            unsigned short* __restrict__ kc) {
  const int gi = blockIdx.x >> 4;       // group
  const int c  = blockIdx.x & 15;       // k-chunk
  const int t = threadIdx.x;
  const int row = t & 127;
  const int part = t >> 7;              // 0/1 (cols 0-31 / 32-63)
  const unsigned short* src =
      qkv + (size_t)(c * 128 + row) * QKVN + KOFF + gi * 64 + part * 32;
  char* dst = (char*)kc + ((size_t)(gi * 16 + c) << 14);
  const int swz = (row & 7) << 4;
#pragma unroll
  for (int j = 0; j < 4; ++j) {
    short8 v = *reinterpret_cast<const short8*>(src + j * 8);
    int b = (row * 128 + part * 64 + j * 16) ^ swz;
    *reinterpret_cast<short8*>(dst + b) = v;
  }
}

// ---------------- V transpose -> swizzled per-(group,chunk) tiles -----------
__global__ __launch_bounds__(256) void k_vT(const unsigned short* __restrict__ qkv,
                                            unsigned short* __restrict__ vt) {
  __shared__ unsigned short tile[64][72];
  const int t = threadIdx.x;
  const int p0 = (blockIdx.x & 31) * 64;
  const int g0 = (blockIdx.x >> 5) * 64;
  {
    const int pl = t >> 3;
    const int gl = (t & 7) * 8;
#pragma unroll
    for (int i = 0; i < 2; i++) {
      int p = pl + i * 32;
      short8 v = *reinterpret_cast<const short8*>(qkv + (size_t)(p0 + p) * QKVN + VOFF + g0 + gl);
#pragma unroll
      for (int j = 0; j < 8; j++) tile[p][gl + j] = (unsigned short)v[j];
    }
  }
  __syncthreads();
  {
    const int gr = t >> 3;
    const int pc = (t & 7) * 8;
    const int cb = pc & ~31;
    const int rbase = pc & 31;
    const int chunk = p0 >> 7;
    const int colin = (p0 & 64) + pc;    // col within 128-chunk
    const int grp = g0 >> 6;
#pragma unroll
    for (int i = 0; i < 2; i++) {
      int g = gr + i * 32;               // row in tile (gd within group)
      short8 o;
#pragma unroll
      for (int j = 0; j < 8; j++) {
        int rp = rbase + j;
        int q8 = rp >> 3, jj = rp & 7;
        int src = cb + ((jj < 4) ? (q8 * 4 + jj) : (16 + q8 * 4 + (jj - 4)));
        o[j] = (short)tile[src][g];
      }
      int b = (g * 256 + colin * 2) ^ ((g & 7) << 4);
      *reinterpret_cast<short8*>(
          (char*)vt + (((size_t)(grp * 16 + chunk)) << 14) + b) = o;
    }
  }
}

// ---------------- fused attention v11: v9 geometry + dbuf + no bpermute -----
// v9 base (proven best: 512 blocks x 8 waves, wave = head x 16 q-rows, XCD-
// pinned group, LDS-staged swizzled tiles) with three deltas:
//  1. bpermute store repack DELETED -> plain f32x4 stores (shape proven
//     neutral r5-r7; removes 1024 LDS-pipe ops/thread + the 2^23 conflicts).
//  2. Double-buffered tiles; STAGE(c+1) issued at TOP of chunk c -> stage
//     latency hidden under compute instead of exposed at the barrier.
//  3. Pass-B end-of-chunk wait = vmcnt(8) lgkmcnt(0): retires the 4 stage
//     loads, leaves this chunk's 8 attn stores in flight across the barrier
//     (in-order vmcnt retires the PREVIOUS chunk's stores instead) -> one
//     full chunk of store-drain/compute overlap, never drain-to-0 in-loop.
__global__ __launch_bounds__(512, 4) void k_attn(
    const unsigned short* __restrict__ qkv, const unsigned short* __restrict__ kc,
    const unsigned short* __restrict__ vt, float* __restrict__ attn_w,
    unsigned short* __restrict__ hout) {
  __shared__ unsigned short Kt[2][8192];   // 2 x 16 KB
  __shared__ unsigned short Vt[2][8192];   // 2 x 16 KB
  const int t = threadIdx.x;
  const int l = t & 63;
  const int w = t >> 6;                    // wave 0..7
  const int g = blockIdx.x & 7;            // group == XCD (round-robin)
  const int bi = blockIdx.x >> 3;          // 0..63
  const int unit = bi * 8 + w;             // 0..511
  const int h = g * 4 + (unit & 3);        // head
  const int r0 = (unit >> 2) * 16;         // q-row base
  const int lr = l & 15;
  const int lg = l >> 4;                   // 0..3
  const int lk = lg * 8;
  const int swz = (lr & 7) << 4;

  // Q fragment = B operand of QK^T (rows r0+lr)
  const unsigned short* qbase = qkv + (size_t)(r0 + lr) * QKVN + h * HDIM + lk;
  const short8 bq0 = *reinterpret_cast<const short8*>(qbase);
  const short8 bq1 = *reinterpret_cast<const short8*>(qbase + 32);

  const char* kcg = (const char*)kc + ((size_t)(g * 16) << 14);
  const char* vtg = (const char*)vt + ((size_t)(g * 16) << 14);

#define STAGE_K(c, b)                                                    \
  { const char* s_ = kcg + ((size_t)(c) << 14);                          \
    char* d_ = (char*)Kt[b];                                             \
    gload_lds16(s_ + t * 16, d_ + t * 16);                               \
    gload_lds16(s_ + 8192 + t * 16, d_ + 8192 + t * 16); }
#define STAGE_V(c, b)                                                    \
  { const char* s_ = vtg + ((size_t)(c) << 14);                          \
    char* d_ = (char*)Vt[b];                                             \
    gload_lds16(s_ + t * 16, d_ + t * 16);                               \
    gload_lds16(s_ + 8192 + t * 16, d_ + 8192 + t * 16); }

  // ================= pass A: online row max + sum (K only, dbuf) ===========
  float m = -1e30f, sm = 0.f;
  STAGE_K(0, 0);
  __syncthreads();
  for (int c = 0; c < 16; ++c) {
    if (c < 15) STAGE_K(c + 1, (c + 1) & 1);   // prefetch overlaps compute
    const char* kb = (const char*)Kt[c & 1];
    f32x4 acc[8];
#pragma unroll
    for (int i = 0; i < 8; ++i) {
      int rb = ((i * 16 + lr) << 7) + (lg << 4);
      short8 a0 = *reinterpret_cast<const short8*>(kb + (rb ^ swz));
      short8 a1 = *reinterpret_cast<const short8*>(kb + ((rb + 64) ^ swz));
      f32x4 a = {};
      a = mfma16(a0, bq0, a);
      a = mfma16(a1, bq1, a);
      acc[i] = a * 0.125f;
    }
    float mc = -1e30f;
#pragma unroll
    for (int i = 0; i < 8; ++i)
      mc = fmaxf(mc, fmaxf(fmaxf(acc[i][0], acc[i][1]), fmaxf(acc[i][2], acc[i][3])));
    mc = fmaxf(mc, __shfl_xor(mc, 16, 64));
    mc = fmaxf(mc, __shfl_xor(mc, 32, 64));
    float nm = fmaxf(m, mc);
    float ps = 0.f;
#pragma unroll
    for (int i = 0; i < 8; ++i) {
#pragma unroll
      for (int r = 0; r < 4; ++r) ps += __expf(acc[i][r] - nm);
    }
    ps += __shfl_xor(ps, 16, 64);
    ps += __shfl_xor(ps, 32, 64);
    sm = sm * __expf(m - nm) + ps;
    m = nm;
    if (c < 15) {
      asm volatile("s_waitcnt vmcnt(0) lgkmcnt(0)\n\ts_barrier" ::: "memory");
      __builtin_amdgcn_sched_barrier(0);
    }
  }
  const float inv = 1.0f / sm;

  // ================= pass B: recompute P, store attn, PV (K+V dbuf) ========
  f32x4 pv0 = {}, pv1 = {}, pv2 = {}, pv3 = {};
  float* aout = attn_w + (size_t)h * S_LEN * S_LEN + (size_t)(r0 + lr) * S_LEN;

  // safe: waves still in pass-A chunk 15 read Kt[1]; we stage Kt[0]/Vt[0]
  STAGE_K(0, 0);
  STAGE_V(0, 0);
  __syncthreads();
  for (int c = 0; c < 16; ++c) {
    const char* kb = (const char*)Kt[c & 1];
    const char* vb = (const char*)Vt[c & 1];
    const int kcol = c * 128;
    union A8 { short8 s; unsigned u[4]; } pa8[4];
    // --- QK^T recompute + normalize + pack ---
#pragma unroll
    for (int i = 0; i < 8; ++i) {
      int rb = ((i * 16 + lr) << 7) + (lg << 4);
      short8 a0 = *reinterpret_cast<const short8*>(kb + (rb ^ swz));
      short8 a1 = *reinterpret_cast<const short8*>(kb + ((rb + 64) ^ swz));
      f32x4 a = {};
      a = mfma16(a0, bq0, a);
      a = mfma16(a1, bq1, a);
      float p0 = __expf(a[0] * 0.125f - m) * inv;
      float p1 = __expf(a[1] * 0.125f - m) * inv;
      float p2 = __expf(a[2] * 0.125f - m) * inv;
      float p3 = __expf(a[3] * 0.125f - m) * inv;
      pa8[i >> 1].u[(i & 1) * 2 + 0] = cvt_pk_bf16(p0, p1);
      pa8[i >> 1].u[(i & 1) * 2 + 1] = cvt_pk_bf16(p2, p3);
    }
    // --- stage next tiles (4 vm loads, BEFORE the 8 stores: in-order vmcnt)
    if (c < 15) { STAGE_K(c + 1, (c + 1) & 1); STAGE_V(c + 1, (c + 1) & 1); }
    // --- attn stores: plain f32x4 from pa8 expansion (no repack) ---
#pragma unroll
    for (int s = 0; s < 4; ++s) {
      f32x4 X, Y;
      X[0] = bf16lo_f32(pa8[s].u[0]); X[1] = bf16hi_f32(pa8[s].u[0]);
      X[2] = bf16lo_f32(pa8[s].u[1]); X[3] = bf16hi_f32(pa8[s].u[1]);
      Y[0] = bf16lo_f32(pa8[s].u[2]); Y[1] = bf16hi_f32(pa8[s].u[2]);
      Y[2] = bf16lo_f32(pa8[s].u[3]); Y[3] = bf16hi_f32(pa8[s].u[3]);
      *reinterpret_cast<f32x4*>(aout + kcol + s * 32 + lg * 4) = X;
      *reinterpret_cast<f32x4*>(aout + kcol + s * 32 + 16 + lg * 4) = Y;
    }
    // --- PV from Vt: one swizzled 16B read per (s, hd-tile) ---
#pragma unroll
    for (int s = 0; s < 4; ++s) {
      int cbyte = s * 64 + (lg << 4);
      short8 b0 = *reinterpret_cast<const short8*>(vb + ((((lr) << 8) + cbyte) ^ swz));
      short8 b1 = *reinterpret_cast<const short8*>(vb + ((((16 + lr) << 8) + cbyte) ^ swz));
      short8 b2 = *reinterpret_cast<const short8*>(vb + ((((32 + lr) << 8) + cbyte) ^ swz));
      short8 b3 = *reinterpret_cast<const short8*>(vb + ((((48 + lr) << 8) + cbyte) ^ swz));
      pv0 = mfma16(pa8[s].s, b0, pv0);
      pv1 = mfma16(pa8[s].s, b1, pv1);
      pv2 = mfma16(pa8[s].s, b2, pv2);
      pv3 = mfma16(pa8[s].s, b3, pv3);
    }
    // --- counted wait: retire stage loads (and last chunk's stores); keep
    //     THIS chunk's 8 stores in flight across the barrier ---
    if (c < 15) {
      asm volatile("s_waitcnt vmcnt(8) lgkmcnt(0)\n\ts_barrier" ::: "memory");
      __builtin_amdgcn_sched_barrier(0);
    }
  }

  // ---- hout: lane holds out[q=lg*4+r][hd=ht*16+lr]; full k -> no reduce ----
  unsigned short* hb = hout + (size_t)(r0 + lg * 4) * EMB + h * HDIM + lr;
#pragma unroll
  for (int r = 0; r < 4; ++r) {
    hb[(size_t)r * EMB +  0] = f2bf(pv0[r]);
    hb[(size_t)r * EMB + 16] = f2bf(pv1[r]);
    hb[(size_t)r * EMB + 32] = f2bf(pv2[r]);
    hb[(size_t)r * EMB + 48] = f2bf(pv3[r]);
  }
#undef STAGE_K
#undef STAGE_V
}

extern "C" void kernel_launch(void* const* d_in, const int* in_sizes, int n_in,
                              void* d_out, int out_size, void* d_ws, size_t ws_size,
                              hipStream_t stream) {
  const float* x  = (const float*)d_in[0];
  const float* Wq = (const float*)d_in[1];
  const float* bq = (const float*)d_in[2];
  const float* Wk = (const float*)d_in[3];
  const float* bk = (const float*)d_in[4];
  const float* Wv = (const float*)d_in[5];
  const float* bv = (const float*)d_in[6];
  const float* Wo = (const float*)d_in[7];
  const float* bo = (const float*)d_in[8];
  float* out = (float*)d_out;

  char* ws = (char*)d_ws;
  unsigned short* x_bf  = (unsigned short*)(ws);                 // 8 MiB
  unsigned short* wqkv  = (unsigned short*)(ws + (8ull  << 20)); // 12 MiB
  unsigned short* wo_bf = (unsigned short*)(ws + (20ull << 20)); // 8 MiB
  float*          bqkv  = (float*)         (ws + (28ull << 20)); // 12 KiB
  unsigned short* qkv   = (unsigned short*)(ws + (29ull << 20)); // 12 MiB
  unsigned short* vt_b  = (unsigned short*)(ws + (41ull << 20)); // 2 MiB
  unsigned short* hout  = (unsigned short*)(ws + (43ull << 20)); // 8 MiB
  unsigned short* kc_b  = (unsigned short*)(ws + (51ull << 20)); // 2 MiB

  k_cvt_all<<<14336, 256, 0, stream>>>(x, Wq, Wk, Wv, Wo, x_bf, wqkv, wo_bf);
  k_bias_cat<<<12, 256, 0, stream>>>(bq, bk, bv, bqkv);

  dim3 g1(16, 24);  // M/128 x N/128
  k_gemm_bt<unsigned short><<<g1, 256, 0, stream>>>(x_bf, wqkv, bqkv, qkv, 2048, 3072, 2048);
  k_kc<<<128, 256, 0, stream>>>(qkv, kc_b);
  k_vT<<<256, 256, 0, stream>>>(qkv, vt_b);
  k_attn<<<512, 512, 0, stream>>>(qkv, kc_b, vt_b, out, hout);
  dim3 g2(16, 16);
  k_gemm_bt<float><<<g2, 256, 0, stream>>>(hout, wo_bf, bo, out + (size_t)NHEAD * S_LEN * S_LEN, 2048, 2048, 2048);
}

// Round 12
// 354.960 us; speedup vs baseline: 1.0593x; 1.0008x over previous
//
#include <hip/hip_runtime.h>
#include <stdint.h>

#define S_LEN 2048
#define EMB   2048
#define NHEAD 32
#define HDIM  64
#define QKVN  3072   // 2048 q + 512 k + 512 v
#define KOFF  2048
#define VOFF  2560

typedef __attribute__((ext_vector_type(8))) short short8;
typedef __attribute__((ext_vector_type(4))) short short4v;
typedef __attribute__((ext_vector_type(4))) float f32x4;

__device__ __forceinline__ unsigned short f2bf(float f) {
  union { float f; unsigned u; } v; v.f = f;
  return (unsigned short)((v.u + 0x7fffu + ((v.u >> 16) & 1u)) >> 16);
}

__device__ __forceinline__ f32x4 mfma16(short8 a, short8 b, f32x4 c) {
  return __builtin_amdgcn_mfma_f32_16x16x32_bf16(a, b, c, 0, 0, 0);
}

__device__ __forceinline__ void gload_lds16(const void* g, void* l) {
  __builtin_amdgcn_global_load_lds(
      (const __attribute__((address_space(1))) void*)g,
      (__attribute__((address_space(3))) void*)l, 16, 0, 0);
}

__device__ __forceinline__ unsigned cvt_pk_bf16(float lo, float hi) {
  unsigned r;
  asm("v_cvt_pk_bf16_f32 %0, %1, %2" : "=v"(r) : "v"(lo), "v"(hi));
  return r;
}

__device__ __forceinline__ float bf16lo_f32(unsigned u) {
  return __builtin_bit_cast(float, u << 16);
}
__device__ __forceinline__ float bf16hi_f32(unsigned u) {
  return __builtin_bit_cast(float, u & 0xffff0000u);
}

// ---------------- fused fp32 -> bf16 convert (all 5 tensors) ----------------
__global__ __launch_bounds__(256) void k_cvt_all(
    const float* __restrict__ x, const float* __restrict__ Wq,
    const float* __restrict__ Wk, const float* __restrict__ Wv,
    const float* __restrict__ Wo, unsigned short* __restrict__ xb,
    unsigned short* __restrict__ wqkv, unsigned short* __restrict__ wob) {
  long i = (long)(blockIdx.x * blockDim.x + threadIdx.x) * 4;
  const float* src; unsigned short* dst; long off;
  if (i < 4194304L)       { src = x;  dst = xb;             off = i; }
  else if (i < 8388608L)  { src = Wq; dst = wqkv;           off = i - 4194304L; }
  else if (i < 9437184L)  { src = Wk; dst = wqkv + 4194304; off = i - 8388608L; }
  else if (i < 10485760L) { src = Wv; dst = wqkv + 5242880; off = i - 9437184L; }
  else                    { src = Wo; dst = wob;            off = i - 10485760L; }
  float4 v = *reinterpret_cast<const float4*>(src + off);
  short4v o;
  o.x = (short)f2bf(v.x); o.y = (short)f2bf(v.y);
  o.z = (short)f2bf(v.z); o.w = (short)f2bf(v.w);
  *reinterpret_cast<short4v*>(dst + off) = o;
}

__global__ void k_bias_cat(const float* __restrict__ bq, const float* __restrict__ bk,
                           const float* __restrict__ bv, float* __restrict__ dst) {
  int i = blockIdx.x * blockDim.x + threadIdx.x;   // grid covers exactly 3072
  if (i < 2048) dst[i] = bq[i];
  else if (i < 2560) dst[i] = bk[i - 2048];
  else dst[i] = bv[i - 2560];
}

// ---------------- GEMM: C[M,N] = A[M,K] @ B[N,K]^T + bias ----------------
template <typename OUT_T>
__global__ __launch_bounds__(256) void k_gemm_bt(
    const unsigned short* __restrict__ A, const unsigned short* __restrict__ B,
    const float* __restrict__ bias, OUT_T* __restrict__ C, int M, int N, int K) {
  __shared__ unsigned short As[128 * 32];
  __shared__ unsigned short Bs[128 * 32];
  const int t = threadIdx.x;
  const int l = t & 63;
  const int w = t >> 6;
  const int m0 = blockIdx.x * 128;
  const int n0 = blockIdx.y * 128;
  const int wm = w >> 1, wn = w & 1;

  f32x4 acc[4][4] = {};

  const unsigned short* ga0 = A + (size_t)(m0 + (t >> 2)) * K + (t & 3) * 8;
  const unsigned short* ga1 = ga0 + (size_t)64 * K;
  const unsigned short* gb0 = B + (size_t)(n0 + (t >> 2)) * K + (t & 3) * 8;
  const unsigned short* gb1 = gb0 + (size_t)64 * K;
  unsigned short* la0 = As + t * 8;
  unsigned short* la1 = As + 2048 + t * 8;
  unsigned short* lb0 = Bs + t * 8;
  unsigned short* lb1 = Bs + 2048 + t * 8;

  const int lr = l & 15;
  const int lk = (l >> 4) * 8;
  const unsigned short* arow = As + (wm * 64 + lr) * 32 + lk;
  const unsigned short* brow = Bs + (wn * 64 + lr) * 32 + lk;

  for (int k0 = 0; k0 < K; k0 += 32) {
    gload_lds16(ga0, la0);
    gload_lds16(ga1, la1);
    gload_lds16(gb0, lb0);
    gload_lds16(gb1, lb1);
    ga0 += 32; ga1 += 32; gb0 += 32; gb1 += 32;
    __syncthreads();
    short8 af[4], bfv[4];
#pragma unroll
    for (int i = 0; i < 4; i++) {
      af[i]  = *reinterpret_cast<const short8*>(arow + i * 16 * 32);
      bfv[i] = *reinterpret_cast<const short8*>(brow + i * 16 * 32);
    }
#pragma unroll
    for (int i = 0; i < 4; i++)
#pragma unroll
      for (int j = 0; j < 4; j++)
        acc[i][j] = mfma16(af[i], bfv[j], acc[i][j]);
    __syncthreads();
  }

  const int lg = l >> 4;
#pragma unroll
  for (int i = 0; i < 4; i++) {
#pragma unroll
    for (int j = 0; j < 4; j++) {
      int col = n0 + wn * 64 + j * 16 + lr;
      float bb = bias[col];
#pragma unroll
      for (int r = 0; r < 4; r++) {
        int row = m0 + wm * 64 + i * 16 + lg * 4 + r;
        float val = acc[i][j][r] + bb;
        if constexpr (sizeof(OUT_T) == 2)
          C[(size_t)row * N + col] = (OUT_T)f2bf(val);
        else
          C[(size_t)row * N + col] = (OUT_T)val;
      }
    }
  }
}

// ---------------- K compaction into swizzled per-(group,chunk) tiles --------
__global__ __launch_bounds__(256) void k_kc(const unsigned short* __restrict__ qkv,
                                            unsigned short* __restrict__ kc) {
  const int gi = blockIdx.x >> 4;       // group
  const int c  = blockIdx.x & 15;       // k-chunk
  const int t = threadIdx.x;
  const int row = t & 127;
  const int part = t >> 7;              // 0/1 (cols 0-31 / 32-63)
  const unsigned short* src =
      qkv + (size_t)(c * 128 + row) * QKVN + KOFF + gi * 64 + part * 32;
  char* dst = (char*)kc + ((size_t)(gi * 16 + c) << 14);
  const int swz = (row & 7) << 4;
#pragma unroll
  for (int j = 0; j < 4; ++j) {
    short8 v = *reinterpret_cast<const short8*>(src + j * 8);
    int b = (row * 128 + part * 64 + j * 16) ^ swz;
    *reinterpret_cast<short8*>(dst + b) = v;
  }
}

// ---------------- V transpose -> swizzled per-(group,chunk) tiles -----------
__global__ __launch_bounds__(256) void k_vT(const unsigned short* __restrict__ qkv,
                                            unsigned short* __restrict__ vt) {
  __shared__ unsigned short tile[64][72];
  const int t = threadIdx.x;
  const int p0 = (blockIdx.x & 31) * 64;
  const int g0 = (blockIdx.x >> 5) * 64;
  {
    const int pl = t >> 3;
    const int gl = (t & 7) * 8;
#pragma unroll
    for (int i = 0; i < 2; i++) {
      int p = pl + i * 32;
      short8 v = *reinterpret_cast<const short8*>(qkv + (size_t)(p0 + p) * QKVN + VOFF + g0 + gl);
#pragma unroll
      for (int j = 0; j < 8; j++) tile[p][gl + j] = (unsigned short)v[j];
    }
  }
  __syncthreads();
  {
    const int gr = t >> 3;
    const int pc = (t & 7) * 8;
    const int cb = pc & ~31;
    const int rbase = pc & 31;
    const int chunk = p0 >> 7;
    const int colin = (p0 & 64) + pc;    // col within 128-chunk
    const int grp = g0 >> 6;
#pragma unroll
    for (int i = 0; i < 2; i++) {
      int g = gr + i * 32;               // row in tile (gd within group)
      short8 o;
#pragma unroll
      for (int j = 0; j < 8; j++) {
        int rp = rbase + j;
        int q8 = rp >> 3, jj = rp & 7;
        int src = cb + ((jj < 4) ? (q8 * 4 + jj) : (16 + q8 * 4 + (jj - 4)));
        o[j] = (short)tile[src][g];
      }
      int b = (g * 256 + colin * 2) ^ ((g & 7) << 4);
      *reinterpret_cast<short8*>(
          (char*)vt + (((size_t)(grp * 16 + chunk)) << 14) + b) = o;
    }
  }
}

// ---------------- fused attention v12: v9 base + plain stores + counted wait
// v9 geometry kept EXACTLY (proven best occupancy: single-buffered 32 KB
// tiles -> 4 blocks/CU; 512 blocks x 8 waves; wave = head x 16 q-rows; XCD-
// pinned group). Two non-LDS-costing deltas:
//  1. bpermute store repack DELETED -> plain f32x4 stores (shape proven
//     neutral r5-r7; removes 1024 LDS-pipe ops/thread + the 2^23 conflicts,
//     which now contend across 4 blocks/CU).
//  2. Chunk tail reordered: LGKM_BAR -> STAGE(c+1) [4 loads] -> stores [8]
//     -> vmcnt(8)+s_barrier. In-order vmcnt retires the stage loads (and the
//     PREVIOUS chunk's stores) while leaving THIS chunk's stores in flight
//     across the barrier: a full chunk of store-drain overlap, no vmcnt(0).
__global__ __launch_bounds__(512, 4) void k_attn(
    const unsigned short* __restrict__ qkv, const unsigned short* __restrict__ kc,
    const unsigned short* __restrict__ vt, float* __restrict__ attn_w,
    unsigned short* __restrict__ hout) {
  __shared__ unsigned short Kt[8192];   // 16 KB
  __shared__ unsigned short Vt[8192];   // 16 KB
  const int t = threadIdx.x;
  const int l = t & 63;
  const int w = t >> 6;                    // wave 0..7
  const int g = blockIdx.x & 7;            // group == XCD (round-robin)
  const int bi = blockIdx.x >> 3;          // 0..63
  const int unit = bi * 8 + w;             // 0..511
  const int h = g * 4 + (unit & 3);        // head
  const int r0 = (unit >> 2) * 16;         // q-row base
  const int lr = l & 15;
  const int lg = l >> 4;                   // 0..3
  const int lk = lg * 8;
  const int swz = (lr & 7) << 4;

  // Q fragment = B operand of QK^T (rows r0+lr)
  const unsigned short* qbase = qkv + (size_t)(r0 + lr) * QKVN + h * HDIM + lk;
  const short8 bq0 = *reinterpret_cast<const short8*>(qbase);
  const short8 bq1 = *reinterpret_cast<const short8*>(qbase + 32);

  const char* kcg = (const char*)kc + ((size_t)(g * 16) << 14);
  const char* vtg = (const char*)vt + ((size_t)(g * 16) << 14);
  char* kdst = (char*)Kt;
  char* vdst = (char*)Vt;
  const char* kldb = (const char*)Kt;
  const char* vldb = (const char*)Vt;

#define STAGE_K(c)                                                      \
  { const char* s_ = kcg + ((size_t)(c) << 14);                         \
    gload_lds16(s_ + t * 16, kdst + t * 16);                            \
    gload_lds16(s_ + 8192 + t * 16, kdst + 8192 + t * 16); }
#define STAGE_V(c)                                                      \
  { const char* s_ = vtg + ((size_t)(c) << 14);                         \
    gload_lds16(s_ + t * 16, vdst + t * 16);                            \
    gload_lds16(s_ + 8192 + t * 16, vdst + 8192 + t * 16); }
#define LGKM_BAR()                                                      \
  asm volatile("s_waitcnt lgkmcnt(0)\n\ts_barrier" ::: "memory");       \
  __builtin_amdgcn_sched_barrier(0);

  // ================= pass A: online row max + sum (K from LDS) =============
  float m = -1e30f, sm = 0.f;
  STAGE_K(0);
  __syncthreads();
  for (int c = 0; c < 16; ++c) {
    f32x4 acc[8];
#pragma unroll
    for (int i = 0; i < 8; ++i) {
      int rb = ((i * 16 + lr) << 7) + (lg << 4);
      short8 a0 = *reinterpret_cast<const short8*>(kldb + (rb ^ swz));
      short8 a1 = *reinterpret_cast<const short8*>(kldb + ((rb + 64) ^ swz));
      f32x4 a = {};
      a = mfma16(a0, bq0, a);
      a = mfma16(a1, bq1, a);
      acc[i] = a * 0.125f;
    }
    float mc = -1e30f;
#pragma unroll
    for (int i = 0; i < 8; ++i)
      mc = fmaxf(mc, fmaxf(fmaxf(acc[i][0], acc[i][1]), fmaxf(acc[i][2], acc[i][3])));
    mc = fmaxf(mc, __shfl_xor(mc, 16, 64));
    mc = fmaxf(mc, __shfl_xor(mc, 32, 64));
    float nm = fmaxf(m, mc);
    float ps = 0.f;
#pragma unroll
    for (int i = 0; i < 8; ++i) {
#pragma unroll
      for (int r = 0; r < 4; ++r) ps += __expf(acc[i][r] - nm);
    }
    ps += __shfl_xor(ps, 16, 64);
    ps += __shfl_xor(ps, 32, 64);
    sm = sm * __expf(m - nm) + ps;
    m = nm;
    LGKM_BAR();                       // all waves done reading Kt
    if (c < 15) STAGE_K(c + 1);
    __syncthreads();                  // vmcnt(0): next tile ready (no stores yet)
  }
  const float inv = 1.0f / sm;

  // ================= pass B: recompute P, PV, stores-overlapped ============
  f32x4 pv0 = {}, pv1 = {}, pv2 = {}, pv3 = {};
  float* aout = attn_w + (size_t)h * S_LEN * S_LEN + (size_t)(r0 + lr) * S_LEN;

  STAGE_K(0);
  STAGE_V(0);
  __syncthreads();
  for (int c = 0; c < 16; ++c) {
    const int kcol = c * 128;
    union A8 { short8 s; unsigned u[4]; } pa8[4];
    // --- QK^T recompute + normalize + pack (LDS reads) ---
#pragma unroll
    for (int i = 0; i < 8; ++i) {
      int rb = ((i * 16 + lr) << 7) + (lg << 4);
      short8 a0 = *reinterpret_cast<const short8*>(kldb + (rb ^ swz));
      short8 a1 = *reinterpret_cast<const short8*>(kldb + ((rb + 64) ^ swz));
      f32x4 a = {};
      a = mfma16(a0, bq0, a);
      a = mfma16(a1, bq1, a);
      float p0 = __expf(a[0] * 0.125f - m) * inv;
      float p1 = __expf(a[1] * 0.125f - m) * inv;
      float p2 = __expf(a[2] * 0.125f - m) * inv;
      float p3 = __expf(a[3] * 0.125f - m) * inv;
      pa8[i >> 1].u[(i & 1) * 2 + 0] = cvt_pk_bf16(p0, p1);
      pa8[i >> 1].u[(i & 1) * 2 + 1] = cvt_pk_bf16(p2, p3);
    }
    // --- PV from Vt (LDS reads) ---
#pragma unroll
    for (int s = 0; s < 4; ++s) {
      int cbyte = s * 64 + (lg << 4);
      short8 b0 = *reinterpret_cast<const short8*>(vldb + ((((lr) << 8) + cbyte) ^ swz));
      short8 b1 = *reinterpret_cast<const short8*>(vldb + ((((16 + lr) << 8) + cbyte) ^ swz));
      short8 b2 = *reinterpret_cast<const short8*>(vldb + ((((32 + lr) << 8) + cbyte) ^ swz));
      short8 b3 = *reinterpret_cast<const short8*>(vldb + ((((48 + lr) << 8) + cbyte) ^ swz));
      pv0 = mfma16(pa8[s].s, b0, pv0);
      pv1 = mfma16(pa8[s].s, b1, pv1);
      pv2 = mfma16(pa8[s].s, b2, pv2);
      pv3 = mfma16(pa8[s].s, b3, pv3);
    }
    // --- all LDS reads done; safe to overwrite tiles ---
    LGKM_BAR();
    if (c < 15) { STAGE_K(c + 1); STAGE_V(c + 1); }   // 4 loads first
    // --- attn stores issued AFTER the stage loads (in-order vmcnt) ---
#pragma unroll
    for (int s = 0; s < 4; ++s) {
      f32x4 X, Y;
      X[0] = bf16lo_f32(pa8[s].u[0]); X[1] = bf16hi_f32(pa8[s].u[0]);
      X[2] = bf16lo_f32(pa8[s].u[1]); X[3] = bf16hi_f32(pa8[s].u[1]);
      Y[0] = bf16lo_f32(pa8[s].u[2]); Y[1] = bf16hi_f32(pa8[s].u[2]);
      Y[2] = bf16lo_f32(pa8[s].u[3]); Y[3] = bf16hi_f32(pa8[s].u[3]);
      *reinterpret_cast<f32x4*>(aout + kcol + s * 32 + lg * 4) = X;
      *reinterpret_cast<f32x4*>(aout + kcol + s * 32 + 16 + lg * 4) = Y;
    }
    // --- counted wait: stage loads (+ previous stores) retire; THIS chunk's
    //     8 stores stay in flight across the barrier ---
    if (c < 15) {
      asm volatile("s_waitcnt vmcnt(8)\n\ts_barrier" ::: "memory");
      __builtin_amdgcn_sched_barrier(0);
    }
  }

  // ---- hout: lane holds out[q=lg*4+r][hd=ht*16+lr]; full k -> no reduce ----
  unsigned short* hb = hout + (size_t)(r0 + lg * 4) * EMB + h * HDIM + lr;
#pragma unroll
  for (int r = 0; r < 4; ++r) {
    hb[(size_t)r * EMB +  0] = f2bf(pv0[r]);
    hb[(size_t)r * EMB + 16] = f2bf(pv1[r]);
    hb[(size_t)r * EMB + 32] = f2bf(pv2[r]);
    hb[(size_t)r * EMB + 48] = f2bf(pv3[r]);
  }
#undef STAGE_K
#undef STAGE_V
#undef LGKM_BAR
}

extern "C" void kernel_launch(void* const* d_in, const int* in_sizes, int n_in,
                              void* d_out, int out_size, void* d_ws, size_t ws_size,
                              hipStream_t stream) {
  const float* x  = (const float*)d_in[0];
  const float* Wq = (const float*)d_in[1];
  const float* bq = (const float*)d_in[2];
  const float* Wk = (const float*)d_in[3];
  const float* bk = (const float*)d_in[4];
  const float* Wv = (const float*)d_in[5];
  const float* bv = (const float*)d_in[6];
  const float* Wo = (const float*)d_in[7];
  const float* bo = (const float*)d_in[8];
  float* out = (float*)d_out;

  char* ws = (char*)d_ws;
  unsigned short* x_bf  = (unsigned short*)(ws);                 // 8 MiB
  unsigned short* wqkv  = (unsigned short*)(ws + (8ull  << 20)); // 12 MiB
  unsigned short* wo_bf = (unsigned short*)(ws + (20ull << 20)); // 8 MiB
  float*          bqkv  = (float*)         (ws + (28ull << 20)); // 12 KiB
  unsigned short* qkv   = (unsigned short*)(ws + (29ull << 20)); // 12 MiB
  unsigned short* vt_b  = (unsigned short*)(ws + (41ull << 20)); // 2 MiB
  unsigned short* hout  = (unsigned short*)(ws + (43ull << 20)); // 8 MiB
  unsigned short* kc_b  = (unsigned short*)(ws + (51ull << 20)); // 2 MiB

  k_cvt_all<<<14336, 256, 0, stream>>>(x, Wq, Wk, Wv, Wo, x_bf, wqkv, wo_bf);
  k_bias_cat<<<12, 256, 0, stream>>>(bq, bk, bv, bqkv);

  dim3 g1(16, 24);  // M/128 x N/128
  k_gemm_bt<unsigned short><<<g1, 256, 0, stream>>>(x_bf, wqkv, bqkv, qkv, 2048, 3072, 2048);
  k_kc<<<128, 256, 0, stream>>>(qkv, kc_b);
  k_vT<<<256, 256, 0, stream>>>(qkv, vt_b);
  k_attn<<<512, 512, 0, stream>>>(qkv, kc_b, vt_b, out, hout);
  dim3 g2(16, 16);
  k_gemm_bt<float><<<g2, 256, 0, stream>>>(hout, wo_bf, bo, out + (size_t)NHEAD * S_LEN * S_LEN, 2048, 2048, 2048);
}

// Round 13
// 332.086 us; speedup vs baseline: 1.1323x; 1.0689x over previous
//
#include <hip/hip_runtime.h>
#include <stdint.h>

#define S_LEN 2048
#define EMB   2048
#define NHEAD 32
#define HDIM  64
#define QKVN  3072   // 2048 q + 512 k + 512 v
#define KOFF  2048
#define VOFF  2560

typedef __attribute__((ext_vector_type(8))) short short8;
typedef __attribute__((ext_vector_type(4))) short short4v;
typedef __attribute__((ext_vector_type(4))) float f32x4;

__device__ __forceinline__ unsigned short f2bf(float f) {
  union { float f; unsigned u; } v; v.f = f;
  return (unsigned short)((v.u + 0x7fffu + ((v.u >> 16) & 1u)) >> 16);
}

__device__ __forceinline__ f32x4 mfma16(short8 a, short8 b, f32x4 c) {
  return __builtin_amdgcn_mfma_f32_16x16x32_bf16(a, b, c, 0, 0, 0);
}

__device__ __forceinline__ void gload_lds16(const void* g, void* l) {
  __builtin_amdgcn_global_load_lds(
      (const __attribute__((address_space(1))) void*)g,
      (__attribute__((address_space(3))) void*)l, 16, 0, 0);
}

__device__ __forceinline__ unsigned cvt_pk_bf16(float lo, float hi) {
  unsigned r;
  asm("v_cvt_pk_bf16_f32 %0, %1, %2" : "=v"(r) : "v"(lo), "v"(hi));
  return r;
}

__device__ __forceinline__ float bperm_f32(int idx_bytes, float v) {
  int r = __builtin_amdgcn_ds_bpermute(idx_bytes, __builtin_bit_cast(int, v));
  return __builtin_bit_cast(float, r);
}

__device__ __forceinline__ float bf16lo_f32(unsigned u) {
  return __builtin_bit_cast(float, u << 16);
}
__device__ __forceinline__ float bf16hi_f32(unsigned u) {
  return __builtin_bit_cast(float, u & 0xffff0000u);
}

// ---------------- fused fp32 -> bf16 convert (all 5 tensors) ----------------
__global__ __launch_bounds__(256) void k_cvt_all(
    const float* __restrict__ x, const float* __restrict__ Wq,
    const float* __restrict__ Wk, const float* __restrict__ Wv,
    const float* __restrict__ Wo, unsigned short* __restrict__ xb,
    unsigned short* __restrict__ wqkv, unsigned short* __restrict__ wob) {
  long i = (long)(blockIdx.x * blockDim.x + threadIdx.x) * 4;
  const float* src; unsigned short* dst; long off;
  if (i < 4194304L)       { src = x;  dst = xb;             off = i; }
  else if (i < 8388608L)  { src = Wq; dst = wqkv;           off = i - 4194304L; }
  else if (i < 9437184L)  { src = Wk; dst = wqkv + 4194304; off = i - 8388608L; }
  else if (i < 10485760L) { src = Wv; dst = wqkv + 5242880; off = i - 9437184L; }
  else                    { src = Wo; dst = wob;            off = i - 10485760L; }
  float4 v = *reinterpret_cast<const float4*>(src + off);
  short4v o;
  o.x = (short)f2bf(v.x); o.y = (short)f2bf(v.y);
  o.z = (short)f2bf(v.z); o.w = (short)f2bf(v.w);
  *reinterpret_cast<short4v*>(dst + off) = o;
}

__global__ void k_bias_cat(const float* __restrict__ bq, const float* __restrict__ bk,
                           const float* __restrict__ bv, float* __restrict__ dst) {
  int i = blockIdx.x * blockDim.x + threadIdx.x;   // grid covers exactly 3072
  if (i < 2048) dst[i] = bq[i];
  else if (i < 2560) dst[i] = bk[i - 2048];
  else dst[i] = bv[i - 2560];
}

// ---------------- GEMM: C[M,N] = A[M,K] @ B[N,K]^T + bias ----------------
template <typename OUT_T>
__global__ __launch_bounds__(256) void k_gemm_bt(
    const unsigned short* __restrict__ A, const unsigned short* __restrict__ B,
    const float* __restrict__ bias, OUT_T* __restrict__ C, int M, int N, int K) {
  __shared__ unsigned short As[128 * 32];
  __shared__ unsigned short Bs[128 * 32];
  const int t = threadIdx.x;
  const int l = t & 63;
  const int w = t >> 6;
  const int m0 = blockIdx.x * 128;
  const int n0 = blockIdx.y * 128;
  const int wm = w >> 1, wn = w & 1;

  f32x4 acc[4][4] = {};

  const unsigned short* ga0 = A + (size_t)(m0 + (t >> 2)) * K + (t & 3) * 8;
  const unsigned short* ga1 = ga0 + (size_t)64 * K;
  const unsigned short* gb0 = B + (size_t)(n0 + (t >> 2)) * K + (t & 3) * 8;
  const unsigned short* gb1 = gb0 + (size_t)64 * K;
  unsigned short* la0 = As + t * 8;
  unsigned short* la1 = As + 2048 + t * 8;
  unsigned short* lb0 = Bs + t * 8;
  unsigned short* lb1 = Bs + 2048 + t * 8;

  const int lr = l & 15;
  const int lk = (l >> 4) * 8;
  const unsigned short* arow = As + (wm * 64 + lr) * 32 + lk;
  const unsigned short* brow = Bs + (wn * 64 + lr) * 32 + lk;

  for (int k0 = 0; k0 < K; k0 += 32) {
    gload_lds16(ga0, la0);
    gload_lds16(ga1, la1);
    gload_lds16(gb0, lb0);
    gload_lds16(gb1, lb1);
    ga0 += 32; ga1 += 32; gb0 += 32; gb1 += 32;
    __syncthreads();
    short8 af[4], bfv[4];
#pragma unroll
    for (int i = 0; i < 4; i++) {
      af[i]  = *reinterpret_cast<const short8*>(arow + i * 16 * 32);
      bfv[i] = *reinterpret_cast<const short8*>(brow + i * 16 * 32);
    }
#pragma unroll
    for (int i = 0; i < 4; i++)
#pragma unroll
      for (int j = 0; j < 4; j++)
        acc[i][j] = mfma16(af[i], bfv[j], acc[i][j]);
    __syncthreads();
  }

  const int lg = l >> 4;
#pragma unroll
  for (int i = 0; i < 4; i++) {
#pragma unroll
    for (int j = 0; j < 4; j++) {
      int col = n0 + wn * 64 + j * 16 + lr;
      float bb = bias[col];
#pragma unroll
      for (int r = 0; r < 4; r++) {
        int row = m0 + wm * 64 + i * 16 + lg * 4 + r;
        float val = acc[i][j][r] + bb;
        if constexpr (sizeof(OUT_T) == 2)
          C[(size_t)row * N + col] = (OUT_T)f2bf(val);
        else
          C[(size_t)row * N + col] = (OUT_T)val;
      }
    }
  }
}

// ---------------- K compaction into swizzled per-(group,chunk) tiles --------
// 16KB tiles of 128 k-rows x 64 dims; byte = (row*128 + col*2) ^ ((row&7)<<4).
// Rows <64 occupy the first 8KB -> each 16KB tile is two contiguous 8KB
// 64-row sub-tiles, addressable as kcg + (c2 << 13) for c2 in [0,32).
__global__ __launch_bounds__(256) void k_kc(const unsigned short* __restrict__ qkv,
                                            unsigned short* __restrict__ kc) {
  const int gi = blockIdx.x >> 4;       // group
  const int c  = blockIdx.x & 15;       // k-chunk (128 rows)
  const int t = threadIdx.x;
  const int row = t & 127;
  const int part = t >> 7;              // 0/1 (cols 0-31 / 32-63)
  const unsigned short* src =
      qkv + (size_t)(c * 128 + row) * QKVN + KOFF + gi * 64 + part * 32;
  char* dst = (char*)kc + ((size_t)(gi * 16 + c) << 14);
  const int swz = (row & 7) << 4;
#pragma unroll
  for (int j = 0; j < 4; ++j) {
    short8 v = *reinterpret_cast<const short8*>(src + j * 8);
    int b = (row * 128 + part * 64 + j * 16) ^ swz;
    *reinterpret_cast<short8*>(dst + b) = v;
  }
}

// ---------------- V transpose -> swizzled 8KB per-(group,64chunk) tiles -----
// vt[g][c2] (c2 in [0,32), 64 k-cols): rows gd 0..63, byte =
// (gd*128 + colp*2) ^ ((gd&7)<<4); colp is sigma-permuted within each 32-col
// block (verified v8/v9) so one 16B read = one PV MFMA B operand.
__global__ __launch_bounds__(256) void k_vT(const unsigned short* __restrict__ qkv,
                                            unsigned short* __restrict__ vt) {
  __shared__ unsigned short tile[64][72];
  const int t = threadIdx.x;
  const int p0 = (blockIdx.x & 31) * 64;   // k-pos base = one 64-chunk
  const int g0 = (blockIdx.x >> 5) * 64;
  {
    const int pl = t >> 3;
    const int gl = (t & 7) * 8;
#pragma unroll
    for (int i = 0; i < 2; i++) {
      int p = pl + i * 32;
      short8 v = *reinterpret_cast<const short8*>(qkv + (size_t)(p0 + p) * QKVN + VOFF + g0 + gl);
#pragma unroll
      for (int j = 0; j < 8; j++) tile[p][gl + j] = (unsigned short)v[j];
    }
  }
  __syncthreads();
  {
    const int gr = t >> 3;
    const int pc = (t & 7) * 8;          // colp base in [0,64)
    const int cb = pc & ~31;
    const int rbase = pc & 31;
    const int chunk2 = blockIdx.x & 31;  // 64-col chunk id
    const int grp = g0 >> 6;
#pragma unroll
    for (int i = 0; i < 2; i++) {
      int g = gr + i * 32;               // row (gd within group)
      short8 o;
#pragma unroll
      for (int j = 0; j < 8; j++) {
        int rp = rbase + j;
        int q8 = rp >> 3, jj = rp & 7;
        int src = cb + ((jj < 4) ? (q8 * 4 + jj) : (16 + q8 * 4 + (jj - 4)));
        o[j] = (short)tile[src][g];
      }
      int b = (g * 128 + pc * 2) ^ ((g & 7) << 4);
      *reinterpret_cast<short8*>(
          (char*)vt + (((size_t)(grp * 32 + chunk2)) << 13) + b) = o;
    }
  }
}

// ---------------- fused attention v13: v9 machinery, 32-waves/CU geometry ---
// v9 kept verbatim: bpermute full-line nt stores (load-bearing post-gather:
// 8 lines/instr vs 16), LGKM_BAR -> STAGE -> syncthreads discipline, XCD-
// pinned groups, two-pass online softmax, PV k-relabeled 16x16x32.
// ONE change: geometry. 64-col chunks -> 8KB K + 8KB V tiles (16KB LDS) ->
// 4-wave 256-thr blocks, grid 1024 = 8 blocks/CU = 32 waves/CU (2x v9's TLP,
// the strongest measured lever: 8->285us, 16->~223us). VGPR capped at 64 via
// __launch_bounds__(256,8).
__global__ __launch_bounds__(256, 8) void k_attn(
    const unsigned short* __restrict__ qkv, const unsigned short* __restrict__ kc,
    const unsigned short* __restrict__ vt, float* __restrict__ attn_w,
    unsigned short* __restrict__ hout) {
  __shared__ unsigned short Kt[4096];   // 8 KB
  __shared__ unsigned short Vt[4096];   // 8 KB
  const int t = threadIdx.x;
  const int l = t & 63;
  const int w = t >> 6;                    // wave 0..3
  const int g = blockIdx.x & 7;            // group == XCD (round-robin)
  const int bi = blockIdx.x >> 3;          // 0..127
  const int unit = bi * 4 + w;             // 0..511
  const int h = g * 4 + (unit & 3);        // head
  const int r0 = (unit >> 2) * 16;         // q-row base
  const int lr = l & 15;
  const int lg = l >> 4;                   // 0..3
  const int lk = lg * 8;
  const int swz = (lr & 7) << 4;

  // Q fragment = B operand of QK^T (rows r0+lr)
  const unsigned short* qbase = qkv + (size_t)(r0 + lr) * QKVN + h * HDIM + lk;
  const short8 bq0 = *reinterpret_cast<const short8*>(qbase);
  const short8 bq1 = *reinterpret_cast<const short8*>(qbase + 32);

  const char* kcg = (const char*)kc + ((size_t)(g * 16) << 14);  // 32 x 8KB
  const char* vtg = (const char*)vt + ((size_t)(g * 32) << 13);  // 32 x 8KB
  char* kdst = (char*)Kt;
  char* vdst = (char*)Vt;
  const char* kldb = (const char*)Kt;
  const char* vldb = (const char*)Vt;

#define STAGE_K(c)                                                      \
  { const char* s_ = kcg + ((size_t)(c) << 13);                         \
    gload_lds16(s_ + t * 16, kdst + t * 16);                            \
    gload_lds16(s_ + 4096 + t * 16, kdst + 4096 + t * 16); }
#define STAGE_V(c)                                                      \
  { const char* s_ = vtg + ((size_t)(c) << 13);                         \
    gload_lds16(s_ + t * 16, vdst + t * 16);                            \
    gload_lds16(s_ + 4096 + t * 16, vdst + 4096 + t * 16); }
#define LGKM_BAR()                                                      \
  asm volatile("s_waitcnt lgkmcnt(0)\n\ts_barrier" ::: "memory");       \
  __builtin_amdgcn_sched_barrier(0);

  // ================= pass A: online row max + sum (K from LDS) =============
  float m = -1e30f, sm = 0.f;
  STAGE_K(0);
  __syncthreads();
  for (int c = 0; c < 32; ++c) {
    f32x4 acc[4];
#pragma unroll
    for (int i = 0; i < 4; ++i) {
      int rb = ((i * 16 + lr) << 7) + (lg << 4);
      short8 a0 = *reinterpret_cast<const short8*>(kldb + (rb ^ swz));
      short8 a1 = *reinterpret_cast<const short8*>(kldb + ((rb + 64) ^ swz));
      f32x4 a = {};
      a = mfma16(a0, bq0, a);
      a = mfma16(a1, bq1, a);
      acc[i] = a * 0.125f;
    }
    float mc = -1e30f;
#pragma unroll
    for (int i = 0; i < 4; ++i)
      mc = fmaxf(mc, fmaxf(fmaxf(acc[i][0], acc[i][1]), fmaxf(acc[i][2], acc[i][3])));
    mc = fmaxf(mc, __shfl_xor(mc, 16, 64));
    mc = fmaxf(mc, __shfl_xor(mc, 32, 64));
    float nm = fmaxf(m, mc);
    float ps = 0.f;
#pragma unroll
    for (int i = 0; i < 4; ++i) {
#pragma unroll
      for (int r = 0; r < 4; ++r) ps += __expf(acc[i][r] - nm);
    }
    ps += __shfl_xor(ps, 16, 64);
    ps += __shfl_xor(ps, 32, 64);
    sm = sm * __expf(m - nm) + ps;
    m = nm;
    LGKM_BAR();                       // all waves done reading Kt
    if (c < 31) STAGE_K(c + 1);
    __syncthreads();                  // vmcnt(0): next tile ready
  }
  const float inv = 1.0f / sm;

  // ================= pass B: recompute P, store attn (bperm), PV ===========
  f32x4 pv0 = {}, pv1 = {}, pv2 = {}, pv3 = {};
  const int jj = l & 7;
  const int rown = l >> 3;
  const int idx0 = ((l & 3) * 16 + rown) * 4;   // bperm source (rows 0-7)
  const int idx1 = idx0 + 32;                   // rows 8-15
  const bool hiq = (l & 4) != 0;
  float* arow0 = attn_w + (size_t)h * S_LEN * S_LEN
               + (size_t)(r0 + rown) * S_LEN + jj * 4;
  float* arow1 = arow0 + 8 * S_LEN;

  STAGE_K(0);
  STAGE_V(0);
  __syncthreads();
  for (int c = 0; c < 32; ++c) {
    const int kcol = c * 64;
    union A8 { short8 s; unsigned u[4]; } pa8[2];
    // --- QK^T recompute + normalize + pack ---
#pragma unroll
    for (int i = 0; i < 4; ++i) {
      int rb = ((i * 16 + lr) << 7) + (lg << 4);
      short8 a0 = *reinterpret_cast<const short8*>(kldb + (rb ^ swz));
      short8 a1 = *reinterpret_cast<const short8*>(kldb + ((rb + 64) ^ swz));
      f32x4 a = {};
      a = mfma16(a0, bq0, a);
      a = mfma16(a1, bq1, a);
      float p0 = __expf(a[0] * 0.125f - m) * inv;
      float p1 = __expf(a[1] * 0.125f - m) * inv;
      float p2 = __expf(a[2] * 0.125f - m) * inv;
      float p3 = __expf(a[3] * 0.125f - m) * inv;
      pa8[i >> 1].u[(i & 1) * 2 + 0] = cvt_pk_bf16(p0, p1);
      pa8[i >> 1].u[(i & 1) * 2 + 1] = cvt_pk_bf16(p2, p3);
    }
    // --- attn stores: bpermute repack -> full 128B lines, nt (v9 verbatim) --
#pragma unroll
    for (int s = 0; s < 2; ++s) {
      f32x4 X, Y;
      X[0] = bf16lo_f32(pa8[s].u[0]); X[1] = bf16hi_f32(pa8[s].u[0]);
      X[2] = bf16lo_f32(pa8[s].u[1]); X[3] = bf16hi_f32(pa8[s].u[1]);
      Y[0] = bf16lo_f32(pa8[s].u[2]); Y[1] = bf16hi_f32(pa8[s].u[2]);
      Y[2] = bf16lo_f32(pa8[s].u[3]); Y[3] = bf16hi_f32(pa8[s].u[3]);
      f32x4 o0, o1;
#pragma unroll
      for (int cc = 0; cc < 4; ++cc) {
        float x0 = bperm_f32(idx0, X[cc]);
        float y0 = bperm_f32(idx0, Y[cc]);
        o0[cc] = hiq ? y0 : x0;
        float x1 = bperm_f32(idx1, X[cc]);
        float y1 = bperm_f32(idx1, Y[cc]);
        o1[cc] = hiq ? y1 : x1;
      }
      __builtin_nontemporal_store(o0, reinterpret_cast<f32x4*>(arow0 + kcol + s * 32));
      __builtin_nontemporal_store(o1, reinterpret_cast<f32x4*>(arow1 + kcol + s * 32));
    }
    // --- PV from Vt: one swizzled 16B read per (s, hd-tile) ---
#pragma unroll
    for (int s = 0; s < 2; ++s) {
      int cbyte = s * 64 + (lg << 4);
      short8 b0 = *reinterpret_cast<const short8*>(vldb + ((((lr) << 7) + cbyte) ^ swz));
      short8 b1 = *reinterpret_cast<const short8*>(vldb + ((((16 + lr) << 7) + cbyte) ^ swz));
      short8 b2 = *reinterpret_cast<const short8*>(vldb + ((((32 + lr) << 7) + cbyte) ^ swz));
      short8 b3 = *reinterpret_cast<const short8*>(vldb + ((((48 + lr) << 7) + cbyte) ^ swz));
      pv0 = mfma16(pa8[s].s, b0, pv0);
      pv1 = mfma16(pa8[s].s, b1, pv1);
      pv2 = mfma16(pa8[s].s, b2, pv2);
      pv3 = mfma16(pa8[s].s, b3, pv3);
    }
    LGKM_BAR();                       // LDS reads done; safe to overwrite
    if (c < 31) { STAGE_K(c + 1); STAGE_V(c + 1); }
    __syncthreads();                  // next tiles ready
  }

  // ---- hout: lane holds out[q=lg*4+r][hd=ht*16+lr]; full k -> no reduce ----
  unsigned short* hb = hout + (size_t)(r0 + lg * 4) * EMB + h * HDIM + lr;
#pragma unroll
  for (int r = 0; r < 4; ++r) {
    hb[(size_t)r * EMB +  0] = f2bf(pv0[r]);
    hb[(size_t)r * EMB + 16] = f2bf(pv1[r]);
    hb[(size_t)r * EMB + 32] = f2bf(pv2[r]);
    hb[(size_t)r * EMB + 48] = f2bf(pv3[r]);
  }
#undef STAGE_K
#undef STAGE_V
#undef LGKM_BAR
}

extern "C" void kernel_launch(void* const* d_in, const int* in_sizes, int n_in,
                              void* d_out, int out_size, void* d_ws, size_t ws_size,
                              hipStream_t stream) {
  const float* x  = (const float*)d_in[0];
  const float* Wq = (const float*)d_in[1];
  const float* bq = (const float*)d_in[2];
  const float* Wk = (const float*)d_in[3];
  const float* bk = (const float*)d_in[4];
  const float* Wv = (const float*)d_in[5];
  const float* bv = (const float*)d_in[6];
  const float* Wo = (const float*)d_in[7];
  const float* bo = (const float*)d_in[8];
  float* out = (float*)d_out;

  char* ws = (char*)d_ws;
  unsigned short* x_bf  = (unsigned short*)(ws);                 // 8 MiB
  unsigned short* wqkv  = (unsigned short*)(ws + (8ull  << 20)); // 12 MiB
  unsigned short* wo_bf = (unsigned short*)(ws + (20ull << 20)); // 8 MiB
  float*          bqkv  = (float*)         (ws + (28ull << 20)); // 12 KiB
  unsigned short* qkv   = (unsigned short*)(ws + (29ull << 20)); // 12 MiB
  unsigned short* vt_b  = (unsigned short*)(ws + (41ull << 20)); // 2 MiB
  unsigned short* hout  = (unsigned short*)(ws + (43ull << 20)); // 8 MiB
  unsigned short* kc_b  = (unsigned short*)(ws + (51ull << 20)); // 2 MiB

  k_cvt_all<<<14336, 256, 0, stream>>>(x, Wq, Wk, Wv, Wo, x_bf, wqkv, wo_bf);
  k_bias_cat<<<12, 256, 0, stream>>>(bq, bk, bv, bqkv);

  dim3 g1(16, 24);  // M/128 x N/128
  k_gemm_bt<unsigned short><<<g1, 256, 0, stream>>>(x_bf, wqkv, bqkv, qkv, 2048, 3072, 2048);
  k_kc<<<128, 256, 0, stream>>>(qkv, kc_b);
  k_vT<<<256, 256, 0, stream>>>(qkv, vt_b);
  k_attn<<<1024, 256, 0, stream>>>(qkv, kc_b, vt_b, out, hout);
  dim3 g2(16, 16);
  k_gemm_bt<float><<<g2, 256, 0, stream>>>(hout, wo_bf, bo, out + (size_t)NHEAD * S_LEN * S_LEN, 2048, 2048, 2048);
}